// Round 7
// baseline (1002.434 us; speedup 1.0000x reference)
//
#include <hip/hip_runtime.h>

// Problem constants (fixed by the reference)
#define NN   50000
#define EE   800000
#define DD   64
#define HH   128
#define KIN  320          // 5 * 64
#define TILE_E 128        // 128 edges/block, 512 threads, LDS 81920 B -> 2 blocks/CU

typedef __bf16 bf16x8 __attribute__((ext_vector_type(8)));
typedef float  f32x4  __attribute__((ext_vector_type(4)));

#if __has_builtin(__builtin_amdgcn_cvt_pk_bf16_f32)
typedef __bf16 bf16x2_t __attribute__((ext_vector_type(2)));
__device__ __forceinline__ unsigned int pk2(float a, float b) {
  union { bf16x2_t v; unsigned int u; } cv;
  cv.v = __builtin_amdgcn_cvt_pk_bf16_f32(a, b);
  return cv.u;
}
__device__ __forceinline__ unsigned short f2bf(float a) {
  return (unsigned short)(pk2(a, a) & 0xFFFFu);
}
#else
__device__ __forceinline__ unsigned short f2bf(float f) {
  union { float f; unsigned int u; } v; v.f = f;
  unsigned int u = v.u + 0x7FFFu + ((v.u >> 16) & 1u);   // RTNE
  return (unsigned short)(u >> 16);
}
__device__ __forceinline__ unsigned int pk2(float a, float b) {
  return (unsigned int)f2bf(a) | ((unsigned int)f2bf(b) << 16);
}
#endif

__device__ __forceinline__ float bitsf(unsigned int u) {
  union { unsigned int u; float f; } v; v.u = u; return v.f;
}
// unpack a u32 holding two bf16 (lo = elem0, hi = elem1) to two f32
__device__ __forceinline__ void ub2(unsigned int u, float& lo, float& hi) {
  lo = bitsf(u << 16); hi = bitsf(u & 0xFFFF0000u);
}
// elementwise bf16 add of two packed pairs -> packed pair
__device__ __forceinline__ unsigned int addbf2(unsigned int a, unsigned int r) {
  float a0, a1, r0, r1; ub2(a, a0, a1); ub2(r, r0, r1);
  return pk2(a0 + r0, a1 + r1);
}

// ---------------------------------------------------------------------------
// Packed psi layout in 16B units with the R6-verified bank-spreading swizzle:
//   raw unit = ((row>>4)*10 + (kk>>5))*64 + (row&15)*4 + ((kk>>3)&3)
//   swizzle:   unit ^= (row>>1)&3     (row = edge index within tile)
// kk regions: [0,128) A_sum -> h1 -> h2; [128,192) h_d[snd]; [192,256)
// h_d[rcv]; [256,320) edge_feat.
// ---------------------------------------------------------------------------
__device__ __forceinline__ int psiIdx(int row, int kk) {
  int u = (((row >> 4) * 10 + (kk >> 5)) << 6) + ((row & 15) << 2) + ((kk >> 3) & 3);
  u ^= (row >> 1) & 3;
  return (u << 3) + (kk & 7);
}

// ---------------------------------------------------------------------------
// Fused prep, 3 block families (grid 4163 x 256):
//  [0,3125):   zero agg; convert h_d fp32 -> bf16 table (t < 400000)
//  [3125,3381): weight transpose fp32 -> bf16 ([n][k] so MFMA frags are 16B runs)
//  [3381,4163): node precompute A_s / A_r (bf16 MFMA, b0 folded into A_s),
//               reads fp32 inputs directly -> no intra-kernel dependency.
// ---------------------------------------------------------------------------
__global__ __launch_bounds__(256) void prep_all(
    const float* __restrict__ hd, const float* __restrict__ hs,
    const float* __restrict__ W0, const float* __restrict__ b0,
    const float* __restrict__ W1, const float* __restrict__ W2,
    unsigned short* __restrict__ hdb,
    unsigned short* __restrict__ WT0, unsigned short* __restrict__ WT1,
    unsigned short* __restrict__ WT2,
    unsigned short* __restrict__ As, unsigned short* __restrict__ Ar,
    float* __restrict__ agg) {
  int b = blockIdx.x;
  int t = b * 256 + threadIdx.x;
  if (b < 3125) {                          // t in [0, 800000)
    *(float4*)(agg + (size_t)t * 4) = (float4){0.f, 0.f, 0.f, 0.f};
    if (t < NN * DD / 8) {                 // 400000 hd-convert jobs
      float4 a = *(const float4*)(hd + (size_t)t * 8);
      float4 c = *(const float4*)(hd + (size_t)t * 8 + 4);
      uint4 w;
      w.x = pk2(a.x, a.y); w.y = pk2(a.z, a.w);
      w.z = pk2(c.x, c.y); w.w = pk2(c.z, c.w);
      *(uint4*)(hdb + (size_t)t * 8) = w;
    }
  } else if (b < 3381) {                   // weights: u in [0, 65536)
    int u = t - 3125 * 256;
    if (u < KIN * HH) {
      int k = u / HH, n2 = u % HH;
      WT0[n2 * KIN + k] = f2bf(W0[u]);
    } else if (u < KIN * HH + HH * HH) {
      int v = u - KIN * HH; int k = v / HH, n2 = v % HH;
      WT1[n2 * HH + k] = f2bf(W1[v]);
    } else {
      int v = u - KIN * HH - HH * HH; int k = v / DD, n2 = v % DD;
      WT2[n2 * HH + k] = f2bf(W2[v]);
    }
  } else {
    // ---- node precompute: A_s[n] = [h_s|h_d][n] @ [W0[0:64);W0[128:192)] + b0
    //                       A_r[n] = [h_s|h_d][n] @ [W0[64:128);W0[192:256)]
    // 64 nodes/block, 4 waves; wave w owns coltiles ctg = 4w..4w+3 of 16
    // (ctg<8 -> A_s cols, else A_r). mfma(A=W0-frag, B=feat-frag):
    // D[outcol][node]: col=lane&15=node, row=quad*4+i=outcol.
    int pb = b - 3381;
    int nb = pb * 64;
    int w  = threadIdx.x >> 6;
    int l  = threadIdx.x & 63, ln = l & 15, quad = l >> 4;

    bf16x8 af[4][4];
    float4 b0v[4];
    #pragma unroll
    for (int ct = 0; ct < 4; ++ct) {
      int ctg  = w * 4 + ct;
      int colt = ((ctg & 7) << 4) + ln;          // A-frag row = lane&15
      int roff = (ctg >= 8) ? 64 : 0;
      #pragma unroll
      for (int k0 = 0; k0 < 4; ++k0) {
        int kb   = k0 * 32 + quad * 8;
        int wrow = ((kb < 64) ? kb : kb + 64) + roff;
        union { unsigned int u[4]; bf16x8 v; } cv;
        #pragma unroll
        for (int j = 0; j < 4; ++j) {
          float fa = W0[(size_t)(wrow + 2 * j) * HH + colt];
          float fb = W0[(size_t)(wrow + 2 * j + 1) * HH + colt];
          cv.u[j] = pk2(fa, fb);
        }
        af[ct][k0] = cv.v;
      }
      if (ctg < 8) b0v[ct] = *(const float4*)&b0[((ctg & 7) << 4) + (quad << 2)];
      else         b0v[ct] = (float4){0.f, 0.f, 0.f, 0.f};
    }

    f32x4 acc[4][4];
    #pragma unroll
    for (int ct = 0; ct < 4; ++ct)
      #pragma unroll
      for (int nt = 0; nt < 4; ++nt) acc[ct][nt] = (f32x4){0, 0, 0, 0};

    #pragma unroll
    for (int nt = 0; nt < 4; ++nt) {
      int node = nb + nt * 16 + ln;
      if (node > NN - 1) node = NN - 1;          // clamp (stores predicated)
      #pragma unroll
      for (int k0 = 0; k0 < 4; ++k0) {
        int kb = k0 * 32 + quad * 8;
        const float* src = (kb < 64) ? (hs + (size_t)node * DD + kb)
                                     : (hd + (size_t)node * DD + (kb - 64));
        float4 v0 = *(const float4*)src;
        float4 v1 = *(const float4*)(src + 4);
        union { unsigned int u[4]; bf16x8 v; } cv;
        cv.u[0] = pk2(v0.x, v0.y); cv.u[1] = pk2(v0.z, v0.w);
        cv.u[2] = pk2(v1.x, v1.y); cv.u[3] = pk2(v1.z, v1.w);
        #pragma unroll
        for (int ct = 0; ct < 4; ++ct)
          acc[ct][nt] = __builtin_amdgcn_mfma_f32_16x16x32_bf16(
              af[ct][k0], cv.v, acc[ct][nt], 0, 0, 0);
      }
    }

    #pragma unroll
    for (int ct = 0; ct < 4; ++ct) {
      int ctg = w * 4 + ct;
      unsigned short* T = (ctg < 8) ? As : Ar;
      int cb = ((ctg & 7) << 4) + (quad << 2);
      #pragma unroll
      for (int nt = 0; nt < 4; ++nt) {
        int node = nb + nt * 16 + ln;
        if (node < NN) {
          float v0 = acc[ct][nt][0] + b0v[ct].x;
          float v1 = acc[ct][nt][1] + b0v[ct].y;
          float v2 = acc[ct][nt][2] + b0v[ct].z;
          float v3 = acc[ct][nt][3] + b0v[ct].w;
          uint2 o; o.x = pk2(v0, v1); o.y = pk2(v2, v3);
          *(uint2*)(T + (size_t)node * HH + cb) = o;
        }
      }
    }
  }
}

// ---------------------------------------------------------------------------
// Fused edge kernel (operand-swapped). 512 threads, 128 edges, LDS 80KB ->
// 2 blocks/CU. Weights = MFMA A-operand (registers); edge data = B-operand
// (LDS, swizzled). D[hcol][edge]: lane owns 1 edge x 4 consecutive hcols ->
// h1/h2 writebacks, A_sum add, di/dj reads are all b64 ops. 4 barriers.
// ---------------------------------------------------------------------------
__global__ __launch_bounds__(512, 4) void edge_mlp(
    const unsigned short* __restrict__ As,   // [N][128] bf16 (b0 folded)
    const unsigned short* __restrict__ Ar,   // [N][128] bf16
    const unsigned short* __restrict__ hdb,  // h_d_prev [N][64] bf16
    const float* __restrict__ ef,            // edge_feat[E][64] fp32
    const int* __restrict__ snd,
    const int* __restrict__ rcv,
    const unsigned short* __restrict__ WT0,  // [128][320] bf16 (k 256.. used)
    const unsigned short* __restrict__ WT1,  // [128][128] bf16
    const float* __restrict__ b1,            // [128]
    const unsigned short* __restrict__ WT2,  // [64][128] bf16
    const float* __restrict__ b2,            // [64]
    float* __restrict__ agg)                 // [N][64] fp32
{
  __shared__ __align__(16) unsigned short psi[TILE_E * KIN];  // 81920 B

  const int tid  = threadIdx.x;
  const int e0   = blockIdx.x * TILE_E;
  const int wv   = tid >> 6;        // 0..7
  const int ln   = tid & 15;
  const int quad = (tid >> 4) & 3;
  const int hctp = wv >> 1;         // L0/L1 hcol-tile pair: 0..3
  const int ebL  = (wv & 1) * 4;    // L0/L1 edge-tile base (x16)
  const int w2ct = wv & 3;          // L2 col tile
  const int ebE  = (wv >> 2) * 4;   // L2 edge-tile base (x16)

  // epilogue receiver rows (L1-hot, hidden under gather)
  int rv[4];
  #pragma unroll
  for (int et = 0; et < 4; ++et) rv[et] = rcv[e0 + (ebE + et) * 16 + ln];

  // ---- gather: 10 chunk-slots/thread in 2 batches of 5 (register staging).
  // slots 0-3: A_sum = A_s[si]+A_r[ri] (128 cols); 4,5: hd[si]; 6,7: hd[ri];
  // 8,9: ef fp32 -> bf16.
  {
    uint4 st[5]; int ua[5];
    #pragma unroll
    for (int k = 0; k < 5; ++k) {
      if (k < 4) {
        int j = tid + k * 512;
        int e = j >> 4, c = j & 15;
        int si = snd[e0 + e], ri = rcv[e0 + e];
        uint4 a = *(const uint4*)(As + (size_t)si * HH + c * 8);
        uint4 r = *(const uint4*)(Ar + (size_t)ri * HH + c * 8);
        st[k].x = addbf2(a.x, r.x); st[k].y = addbf2(a.y, r.y);
        st[k].z = addbf2(a.z, r.z); st[k].w = addbf2(a.w, r.w);
        ua[k] = psiIdx(e, c * 8);
      } else {                               // hd_i, edges 0-63
        int e = tid >> 3, c = tid & 7;
        st[k] = *(const uint4*)(hdb + (size_t)snd[e0 + e] * DD + c * 8);
        ua[k] = psiIdx(e, 128 + c * 8);
      }
    }
    #pragma unroll
    for (int k = 0; k < 5; ++k) *(uint4*)&psi[ua[k]] = st[k];
    #pragma unroll
    for (int k = 5; k < 10; ++k) {
      uint4 v; int u;
      if (k == 5) {                          // hd_i, edges 64-127
        int e = 64 + (tid >> 3), c = tid & 7;
        v = *(const uint4*)(hdb + (size_t)snd[e0 + e] * DD + c * 8);
        u = psiIdx(e, 128 + c * 8);
      } else if (k < 8) {                    // hd_j
        int idx = tid + (k - 6) * 512;
        int e = idx >> 3, c = idx & 7;
        v = *(const uint4*)(hdb + (size_t)rcv[e0 + e] * DD + c * 8);
        u = psiIdx(e, 192 + c * 8);
      } else {                               // ef (sequential)
        int idx = tid + (k - 8) * 512;
        int e = idx >> 3, c = idx & 7;
        const float* s = ef + (size_t)(e0 + e) * DD + c * 8;
        float4 v0 = *(const float4*)s, v1 = *(const float4*)(s + 4);
        v.x = pk2(v0.x, v0.y); v.y = pk2(v0.z, v0.w);
        v.z = pk2(v1.x, v1.y); v.w = pk2(v1.z, v1.w);
        u = psiIdx(e, 256 + c * 8);
      }
      st[k - 5] = v; ua[k - 5] = u;
    }
    #pragma unroll
    for (int k = 0; k < 5; ++k) *(uint4*)&psi[ua[k]] = st[k];
  }

  // L0 weight A-frags (ef-part of W0), loaded before the barrier
  bf16x8 wa[2][2];
  #pragma unroll
  for (int hh = 0; hh < 2; ++hh)
    #pragma unroll
    for (int k2 = 0; k2 < 2; ++k2)
      wa[hh][k2] = *(const bf16x8*)(WT0
          + (size_t)((hctp * 2 + hh) * 16 + ln) * KIN + 256 + k2 * 32 + quad * 8);
  __syncthreads();                               // (1) gather complete

  f32x4 acc[2][4];
  #pragma unroll
  for (int hh = 0; hh < 2; ++hh)
    #pragma unroll
    for (int et = 0; et < 4; ++et) acc[hh][et] = (f32x4){0, 0, 0, 0};

  // ---- Layer 0 (K=64, ef only): D[hcol][edge]
  #pragma unroll
  for (int k2 = 0; k2 < 2; ++k2)
    #pragma unroll
    for (int et = 0; et < 4; ++et) {
      bf16x8 bfr = *(const bf16x8*)&psi[psiIdx((ebL + et) * 16 + ln,
                                               256 + k2 * 32 + quad * 8)];
      acc[0][et] = __builtin_amdgcn_mfma_f32_16x16x32_bf16(wa[0][k2], bfr, acc[0][et], 0, 0, 0);
      acc[1][et] = __builtin_amdgcn_mfma_f32_16x16x32_bf16(wa[1][k2], bfr, acc[1][et], 0, 0, 0);
    }

  // h1 = relu(acc + A_sum), in-place b64 RMW (exclusive per-lane ownership;
  // disjoint from the ef region other waves still read -> no barrier needed)
  #pragma unroll
  for (int hh = 0; hh < 2; ++hh)
    #pragma unroll
    for (int et = 0; et < 4; ++et) {
      int e  = (ebL + et) * 16 + ln;
      int bi = psiIdx(e, (hctp * 2 + hh) * 16 + quad * 4);
      uint2 aw = *(uint2*)&psi[bi];
      float f0, f1, f2, f3; ub2(aw.x, f0, f1); ub2(aw.y, f2, f3);
      float v0 = fmaxf(acc[hh][et][0] + f0, 0.f);
      float v1 = fmaxf(acc[hh][et][1] + f1, 0.f);
      float v2 = fmaxf(acc[hh][et][2] + f2, 0.f);
      float v3 = fmaxf(acc[hh][et][3] + f3, 0.f);
      uint2 o; o.x = pk2(v0, v1); o.y = pk2(v2, v3);
      *(uint2*)&psi[bi] = o;
    }

  // L1 weight frags + bias, before the barrier
  bf16x8 wb[2][4];
  #pragma unroll
  for (int hh = 0; hh < 2; ++hh)
    #pragma unroll
    for (int k0 = 0; k0 < 4; ++k0)
      wb[hh][k0] = *(const bf16x8*)(WT1
          + (size_t)((hctp * 2 + hh) * 16 + ln) * HH + k0 * 32 + quad * 8);
  float4 b1v[2];
  #pragma unroll
  for (int hh = 0; hh < 2; ++hh)
    b1v[hh] = *(const float4*)&b1[(hctp * 2 + hh) * 16 + quad * 4];
  __syncthreads();                               // (2) h1 complete

  // ---- Layer 1 (K=128)
  #pragma unroll
  for (int hh = 0; hh < 2; ++hh)
    #pragma unroll
    for (int et = 0; et < 4; ++et) acc[hh][et] = (f32x4){0, 0, 0, 0};
  #pragma unroll
  for (int k0 = 0; k0 < 4; ++k0)
    #pragma unroll
    for (int et = 0; et < 4; ++et) {
      bf16x8 bfr = *(const bf16x8*)&psi[psiIdx((ebL + et) * 16 + ln,
                                               k0 * 32 + quad * 8)];
      acc[0][et] = __builtin_amdgcn_mfma_f32_16x16x32_bf16(wb[0][k0], bfr, acc[0][et], 0, 0, 0);
      acc[1][et] = __builtin_amdgcn_mfma_f32_16x16x32_bf16(wb[1][k0], bfr, acc[1][et], 0, 0, 0);
    }

  // L2 weight frags + bias, before the barrier
  bf16x8 wc[4];
  #pragma unroll
  for (int k0 = 0; k0 < 4; ++k0)
    wc[k0] = *(const bf16x8*)(WT2 + (size_t)(w2ct * 16 + ln) * HH + k0 * 32 + quad * 8);
  float4 b2v = *(const float4*)&b2[w2ct * 16 + quad * 4];
  __syncthreads();                               // (3) all L1 B-reads done

  // h2 = relu(acc + b1), b64 writes into kk[0,128)
  #pragma unroll
  for (int hh = 0; hh < 2; ++hh)
    #pragma unroll
    for (int et = 0; et < 4; ++et) {
      int e  = (ebL + et) * 16 + ln;
      int bi = psiIdx(e, (hctp * 2 + hh) * 16 + quad * 4);
      float v0 = fmaxf(acc[hh][et][0] + b1v[hh].x, 0.f);
      float v1 = fmaxf(acc[hh][et][1] + b1v[hh].y, 0.f);
      float v2 = fmaxf(acc[hh][et][2] + b1v[hh].z, 0.f);
      float v3 = fmaxf(acc[hh][et][3] + b1v[hh].w, 0.f);
      uint2 o; o.x = pk2(v0, v1); o.y = pk2(v2, v3);
      *(uint2*)&psi[bi] = o;
    }
  __syncthreads();                               // (4) h2 complete

  // ---- Layer 2 (K=128) + s_ij + atomic scatter
  f32x4 a2[4];
  #pragma unroll
  for (int et = 0; et < 4; ++et) a2[et] = (f32x4){0, 0, 0, 0};
  #pragma unroll
  for (int k0 = 0; k0 < 4; ++k0)
    #pragma unroll
    for (int et = 0; et < 4; ++et) {
      bf16x8 bfr = *(const bf16x8*)&psi[psiIdx((ebE + et) * 16 + ln,
                                               k0 * 32 + quad * 8)];
      a2[et] = __builtin_amdgcn_mfma_f32_16x16x32_bf16(wc[k0], bfr, a2[et], 0, 0, 0);
    }
  #pragma unroll
  for (int et = 0; et < 4; ++et) {
    int e = (ebE + et) * 16 + ln;
    uint2 du = *(uint2*)&psi[psiIdx(e, 128 + w2ct * 16 + quad * 4)];
    uint2 dv = *(uint2*)&psi[psiIdx(e, 192 + w2ct * 16 + quad * 4)];
    float di0, di1, di2, di3, dj0, dj1, dj2, dj3;
    ub2(du.x, di0, di1); ub2(du.y, di2, di3);
    ub2(dv.x, dj0, dj1); ub2(dv.y, dj2, dj3);
    float p0 = fmaxf(a2[et][0] + b2v.x, 0.f);
    float p1 = fmaxf(a2[et][1] + b2v.y, 0.f);
    float p2 = fmaxf(a2[et][2] + b2v.z, 0.f);
    float p3 = fmaxf(a2[et][3] + b2v.w, 0.f);
    size_t base = (size_t)rv[et] * DD + w2ct * 16 + quad * 4;
    atomicAdd(&agg[base + 0], p0 * (dj0 - di0));
    atomicAdd(&agg[base + 1], p1 * (dj1 - di1));
    atomicAdd(&agg[base + 2], p2 * (dj2 - di2));
    atomicAdd(&agg[base + 3], p3 * (dj3 - di3));
  }
}

// ---------------------------------------------------------------------------
// out = h_d_prev + agg @ Wm  (fp32). 16 rows/block, LDS-staged agg (stride 72
// swizzle: conflict-free broadcast) + float4 Wm reads. Grid 3125.
// ---------------------------------------------------------------------------
__global__ __launch_bounds__(256) void final_out(
    const float* __restrict__ hd,
    const float* __restrict__ agg,
    const float* __restrict__ Wm,   // [64][64] fp32
    float* __restrict__ out)
{
  __shared__ float wmf[DD * DD];    // 16 KB
  __shared__ float arow[16 * 72];   // 4.5 KB, stride-72 swizzle
  int tid = threadIdx.x;
  const float4* wm4 = (const float4*)Wm;
  float4* wf4 = (float4*)wmf;
  #pragma unroll
  for (int i = tid; i < DD * DD / 4; i += 256) wf4[i] = wm4[i];

  int r0 = blockIdx.x * 16;
  {
    float4 av = *(const float4*)(agg + (size_t)r0 * DD + tid * 4);
    int rr = tid >> 4, cc = (tid & 15) * 4;       // tid*4 == rr*64 + cc
    *(float4*)&arow[rr * 72 + cc] = av;
  }
  __syncthreads();

  int row = tid >> 4;
  int cq  = (tid & 15) * 4;
  f32x4 acc = (f32x4){0, 0, 0, 0};
  #pragma unroll
  for (int k = 0; k < DD; ++k) {
    float a = arow[row * 72 + k];
    f32x4 w = *(const f32x4*)&wmf[k * DD + cq];
    acc += a * w;
  }
  size_t o = ((size_t)(r0 + row)) * DD + cq;
  f32x4 h = *(const f32x4*)(hd + o);
  *(f32x4*)(out + o) = h + acc;
}

// ---------------------------------------------------------------------------
extern "C" void kernel_launch(void* const* d_in, const int* in_sizes, int n_in,
                              void* d_out, int out_size, void* d_ws, size_t ws_size,
                              hipStream_t stream) {
  const float* hd = (const float*)d_in[0];
  const float* hs = (const float*)d_in[1];
  const float* ef = (const float*)d_in[2];
  const int* snd  = (const int*)d_in[3];
  const int* rcv  = (const int*)d_in[4];
  const float* W0 = (const float*)d_in[5];
  const float* b0 = (const float*)d_in[6];
  const float* W1 = (const float*)d_in[7];
  const float* b1 = (const float*)d_in[8];
  const float* W2 = (const float*)d_in[9];
  const float* b2 = (const float*)d_in[10];
  const float* Wm = (const float*)d_in[11];
  float* out      = (float*)d_out;

  char* ws = (char*)d_ws;
  float* agg = (float*)ws;                                   // 12,800,000 B
  unsigned short* WT0 = (unsigned short*)(ws + 12800000);    //     81,920 B
  unsigned short* WT1 = WT0 + KIN * HH;                      //     32,768 B
  unsigned short* WT2 = WT1 + HH * HH;                       //     16,384 B
  unsigned short* hdb = (unsigned short*)(ws + 12931072);    //  6,400,000 B
  unsigned short* As  = (unsigned short*)(ws + 19331072);    // 12,800,000 B
  unsigned short* Ar  = (unsigned short*)(ws + 32131072);    // 12,800,000 B
                                                             // total ~44.9 MB
  prep_all<<<4163, 256, 0, stream>>>(hd, hs, W0, b0, W1, W2,
                                     hdb, WT0, WT1, WT2, As, Ar, agg);
  edge_mlp<<<EE / TILE_E, 512, 0, stream>>>(As, Ar, hdb, ef, snd, rcv,
                                            WT0, WT1, b1, WT2, b2, agg);
  final_out<<<NN / 16, 256, 0, stream>>>(hd, agg, Wm, out);
}